// Round 15
// baseline (198.433 us; speedup 1.0000x reference)
//
#include <hip/hip_runtime.h>
#include <stdint.h>
#include <limits.h>

// ---------------------------------------------------------------------------
// RPN loss, bit-exact replication of the JAX reference (incl. threefry PRNG).
// Round 23 == Round 22 resubmitted VERBATIM (r22 got "container failed
// twice" -- infra error, no test verdict; audit found no hang/OOB mechanism;
// precedent r12->r13 and r16->r17 both ran after verbatim resubmit).
//
// Design (r22): r21 reproduced r14's optimum (K1 57us, total 146.5).
// Evidence across r17-r20: K1 is stall-dominated and the stall responds to
// IN-THREAD work per DS op (r20 halved per-thread work -> worse; occupancy
// irrelevant). This round raises it deliberately: 2 anchors/thread
// (a, a+256) against a shared gt stream:
//   - the 2 ds_read_b64/iter are SHARED by both anchors (DS reads/anchor /2)
//   - per-g packs combine in-register -> ONE ds_atomicMax/iter for 2 anchors
//   - two independent FP chains = ILP-2 latency filler (no occupancy bet)
// Per-anchor semantics identical (independent blp, same pack tie-breaks).
// Grid 1152->576 (512 anchors/block), per-image arrivals 144->72.
// Tails + K2 byte-identical to r21 (proven; don't re-roll working codegen).
// ---------------------------------------------------------------------------
#define PARTITIONABLE 1

#define B_ 8
#define K_ 9
#define H_ 64
#define W_ 64
#define G_ 128
#define A_ 36864            // K*H*W
#define HALF_A 18432
#define NBUCK 1024          // buckets over 23-bit v (v>>13)
#define BSHIFT 13
#define CAP 1024            // cutoff-bucket candidate capacity (expected ~40)
#define NB1   576           // K1 grid: (A_/512) * B_
#define NPB1  72            // K1 blocks per image = A_/512
#define NLAB  1152          // K2 grid: (A_/256) * B_
#define NPB   144           // K2 blocks per image

struct KeyParams { uint32_t k[B_][4]; };   // per image: k1.(0,1), k2.(0,1)

__host__ __device__ static inline uint32_t rotl32(uint32_t x, int r) {
  return (x << r) | (x >> (32 - r));
}

// JAX threefry2x32: 20 rounds, key injections every 4 rounds.
__host__ __device__ static inline void tf2x32(uint32_t k0, uint32_t k1,
                                              uint32_t x0, uint32_t x1,
                                              uint32_t& o0, uint32_t& o1) {
  uint32_t ks2 = k0 ^ k1 ^ 0x1BD11BDAu;
  x0 += k0; x1 += k1;
#define TF_R(r) { x0 += x1; x1 = rotl32(x1, r); x1 ^= x0; }
  TF_R(13) TF_R(15) TF_R(26) TF_R(6)
  x0 += k1;  x1 += ks2 + 1u;
  TF_R(17) TF_R(29) TF_R(16) TF_R(24)
  x0 += ks2; x1 += k0 + 2u;
  TF_R(13) TF_R(15) TF_R(26) TF_R(6)
  x0 += k0;  x1 += k1 + 3u;
  TF_R(17) TF_R(29) TF_R(16) TF_R(24)
  x0 += k1;  x1 += ks2 + 4u;
  TF_R(13) TF_R(15) TF_R(26) TF_R(6)
  x0 += ks2; x1 += k0 + 5u;
#undef TF_R
  o0 = x0; o1 = x1;
}

// 23-bit sort key of jax.random.uniform(key,(A,))[a]; score monotone in v,
// score ties <=> equal v (stable argsort -> smaller index ranks first).
__device__ static inline uint32_t anchor_vbits(uint32_t k0, uint32_t k1, int a) {
  uint32_t o0, o1;
#if PARTITIONABLE
  tf2x32(k0, k1, 0u, (uint32_t)a, o0, o1);
  return (o0 ^ o1) >> 9;
#else
  if (a < HALF_A) { tf2x32(k0, k1, (uint32_t)a, (uint32_t)(a + HALF_A), o0, o1); return o0 >> 9; }
  else            { tf2x32(k0, k1, (uint32_t)(a - HALF_A), (uint32_t)a, o0, o1); return o1 >> 9; }
#endif
}

// Box area, contraction off (bit-identical to XLA's plain fp32 ops).
__device__ static inline float area_of(float x0, float y0, float x1, float y1) {
#pragma clang fp contract(off)
  return (x1 - x0) * (y1 - y0);
}

// IoU with anchor area hoisted (bit-identical product order, XLA op-by-op).
__device__ static inline float iou_pre_a(float a0, float a1, float a2, float a3,
                                         float area_a,
                                         float g0, float g1, float g2, float g3) {
#pragma clang fp contract(off)
  float ltx = fmaxf(a0, g0), lty = fmaxf(a1, g1);
  float rbx = fminf(a2, g2), rby = fminf(a3, g3);
  float w = rbx - ltx; w = (w < 0.f) ? 0.f : w;
  float h = rby - lty; h = (h < 0.f) ? 0.f : h;
  float inter  = w * h;
  float area_g = (g2 - g0) * (g3 - g1);
  return inter / (area_a + area_g - inter + 1e-6f);
}

__device__ static inline void encode4(float4 an, float4 gg, float* tt) {
#pragma clang fp contract(off)
  float aw  = an.z - an.x,            ah  = an.w - an.y;
  float acx = (an.x + an.z) * 0.5f,   acy = (an.y + an.w) * 0.5f;
  float gw  = gg.z - gg.x,            gh  = gg.w - gg.y;
  float gcx = (gg.x + gg.z) * 0.5f,   gcy = (gg.y + gg.w) * 0.5f;
  tt[0] = (gcx - acx) / aw;
  tt[1] = (gcy - acy) / ah;
  tt[2] = logf(gw / aw);
  tt[3] = logf(gh / ah);
}

__device__ static inline float block_reduce_float(float v, float* sh) {
  int t = threadIdx.x;
  sh[t] = v; __syncthreads();
  for (int s = 128; s > 0; s >>= 1) { if (t < s) sh[t] += sh[t + s]; __syncthreads(); }
  float r = sh[0]; __syncthreads();
  return r;
}

// Agent-scope (LLC-direct, L2-bypass) relaxed stores/loads: plain-store cost,
// no cache maintenance ops. Used for data a cross-XCD tail block must read.
__device__ static inline void st_agent_i32(int* p, int v) {
  __hip_atomic_store(p, v, __ATOMIC_RELAXED, __HIP_MEMORY_SCOPE_AGENT);
}
__device__ static inline void st_agent_u32(uint32_t* p, uint32_t v) {
  __hip_atomic_store(p, v, __ATOMIC_RELAXED, __HIP_MEMORY_SCOPE_AGENT);
}
__device__ static inline int ld_agent_i32(const int* p) {
  return __hip_atomic_load(p, __ATOMIC_RELAXED, __HIP_MEMORY_SCOPE_AGENT);
}
__device__ static inline uint32_t ld_agent_u32(const uint32_t* p) {
  return __hip_atomic_load(p, __ATOMIC_RELAXED, __HIP_MEMORY_SCOPE_AGENT);
}
__device__ static inline unsigned long long ld_agent_u64(const unsigned long long* p) {
  return __hip_atomic_load(p, __ATOMIC_RELAXED, __HIP_MEMORY_SCOPE_AGENT);
}
__device__ static inline float ld_agent_f32(const float* p) {
  return __hip_atomic_load(p, __ATOMIC_RELAXED, __HIP_MEMORY_SCOPE_AGENT);
}

// ---------------------------------------------------------------------------
// K1: IoU (2 anchors/thread, shared gt reads, fused slot atomic) + per-image
//     tail {force, cutoff} (parallel lanes, O(small)).
// ---------------------------------------------------------------------------
__global__ __launch_bounds__(256) void iou_k(
    const float* __restrict__ anchors, const float* __restrict__ gtb,
    int* __restrict__ labels, int* __restrict__ mgt,
    uint32_t* __restrict__ vpos, uint32_t* __restrict__ vneg,
    int* __restrict__ ghist, int* __restrict__ counts,
    unsigned long long* __restrict__ gmax,
    int* __restrict__ cbR, int* __restrict__ targets,
    int* __restrict__ tickets, KeyParams kp) {
  __shared__ float2 gp01[2 * G_];               // (x0,y0), duplicated for mod-free idx
  __shared__ float2 gp23[2 * G_];               // (x1,y1), duplicated
  __shared__ unsigned long long slot2[2 * G_];  // per-(block,g residue) best pack
  __shared__ int red[256];
  __shared__ int sup[16];
  __shared__ int last;

  const int bid = blockIdx.x;
  const int t = threadIdx.x;
  const int b  = bid / NPB1;
  const int xb = bid % NPB1;
  const int a0 = xb * 512 + t;                   // < A_ exactly
  const int a1 = a0 + 256;
  const size_t idx0 = (size_t)b * A_ + a0;
  const size_t idx1 = idx0 + 256;

  // ========== phase 1: IoU + labels + PRNG + hist + counts ================
  {
    if (t < G_) {
      float4 gg = ((const float4*)gtb)[b * G_ + t];
      float2 p01; p01.x = gg.x; p01.y = gg.y;
      float2 p23; p23.x = gg.z; p23.y = gg.w;
      gp01[t] = p01; gp01[t + G_] = p01;
      gp23[t] = p23; gp23[t + G_] = p23;
    }
    slot2[t] = 0ull;                             // covers all 256 residues
    __syncthreads();

    float4 an0 = ((const float4*)anchors)[a0];
    float4 an1 = ((const float4*)anchors)[a1];
    float area0 = area_of(an0.x, an0.y, an0.z, an0.w);
    float area1 = area_of(an1.x, an1.y, an1.z, an1.w);
    const int t7 = t & (G_ - 1);
    const unsigned long long alow0 = (unsigned long long)(~(uint32_t)a0);
    const unsigned long long alow1 = (unsigned long long)(~(uint32_t)a1);
    unsigned long long blp0 = 0ull, blp1 = 0ull; // (iou_bits<<32 | g^127) max
#pragma unroll 4
    for (int s = 0; s < G_; s++) {
      const int gi = t7 + s;                     // in [0, 254]; g = gi & 127
      float2 p01 = gp01[gi];
      float2 p23 = gp23[gi];
      float v0 = iou_pre_a(an0.x, an0.y, an0.z, an0.w, area0,
                           p01.x, p01.y, p23.x, p23.y);
      float v1 = iou_pre_a(an1.x, an1.y, an1.z, an1.w, area1,
                           p01.x, p01.y, p23.x, p23.y);
      unsigned long long hi0 = (unsigned long long)__float_as_uint(v0) << 32;
      unsigned long long hi1 = (unsigned long long)__float_as_uint(v1) << 32;
      unsigned long long gx  = (unsigned)((gi & (G_ - 1)) ^ (G_ - 1));
      unsigned long long lp0 = hi0 | gx;
      unsigned long long lp1 = hi1 | gx;
      if (lp0 > blp0) blp0 = lp0;                // (higher iou, then smaller g)
      if (lp1 > blp1) blp1 = lp1;
      unsigned long long s0 = hi0 | alow0;       // fused per-g candidate:
      unsigned long long s1 = hi1 | alow1;       // max keeps (iou, smallest a)
      atomicMax(&slot2[gi], s0 > s1 ? s0 : s1);  // ONE atomic for 2 anchors
    }
    __syncthreads();
    if (t < G_) {
      unsigned long long p = slot2[t];
      unsigned long long q = slot2[t + G_];
      if (q > p) p = q;
      atomicMax(&gmax[b * G_ + t], p);           // once per (block, g)
    }

    // ---- per-anchor finish, anchor 0 ----
    {
      float bv = __uint_as_float((uint32_t)(blp0 >> 32));
      int   bi = ((int)(blp0 & (unsigned long long)(G_ - 1))) ^ (G_ - 1);
      int lb = (bv < 0.3f) ? 0 : ((bv >= 0.7f) ? 1 : -1);
      uint32_t vp = anchor_vbits(kp.k[b][0], kp.k[b][1], a0);
      uint32_t vn = anchor_vbits(kp.k[b][2], kp.k[b][3], a0);
      st_agent_i32(&labels[idx0], lb);
      st_agent_u32(&vpos[idx0], vp);
      st_agent_u32(&vneg[idx0], vn);
      mgt[idx0] = bi;
      if (lb == 1)      atomicAdd(&ghist[(b * 2 + 0) * NBUCK + (vp >> BSHIFT)], 1);
      else if (lb == 0) atomicAdd(&ghist[(b * 2 + 1) * NBUCK + (vn >> BSHIFT)], 1);
      unsigned long long mpos = __ballot(lb == 1);
      unsigned long long mneg = __ballot(lb == 0);
      if ((t & 63) == 0) {
        if (mpos) atomicAdd(&counts[b * 2 + 0], __popcll(mpos));
        if (mneg) atomicAdd(&counts[b * 2 + 1], __popcll(mneg));
      }
    }
    // ---- per-anchor finish, anchor 1 ----
    {
      float bv = __uint_as_float((uint32_t)(blp1 >> 32));
      int   bi = ((int)(blp1 & (unsigned long long)(G_ - 1))) ^ (G_ - 1);
      int lb = (bv < 0.3f) ? 0 : ((bv >= 0.7f) ? 1 : -1);
      uint32_t vp = anchor_vbits(kp.k[b][0], kp.k[b][1], a1);
      uint32_t vn = anchor_vbits(kp.k[b][2], kp.k[b][3], a1);
      st_agent_i32(&labels[idx1], lb);
      st_agent_u32(&vpos[idx1], vp);
      st_agent_u32(&vneg[idx1], vn);
      mgt[idx1] = bi;
      if (lb == 1)      atomicAdd(&ghist[(b * 2 + 0) * NBUCK + (vp >> BSHIFT)], 1);
      else if (lb == 0) atomicAdd(&ghist[(b * 2 + 1) * NBUCK + (vn >> BSHIFT)], 1);
      unsigned long long mpos = __ballot(lb == 1);
      unsigned long long mneg = __ballot(lb == 0);
      if ((t & 63) == 0) {
        if (mpos) atomicAdd(&counts[b * 2 + 0], __popcll(mpos));
        if (mneg) atomicAdd(&counts[b * 2 + 1], __popcll(mneg));
      }
    }
  }

  // ---- per-image ticket: syncthreads drains vmcnt (stores acked at LLC) --
  __syncthreads();
  if (t == 0) {
    int v = __hip_atomic_fetch_add(&tickets[b], 1, __ATOMIC_RELAXED,
                                   __HIP_MEMORY_SCOPE_AGENT);
    last = (v == NPB1 - 1);
  }
  __syncthreads();
  if (!last) return;

  // ========== tail (last image-b block): force best anchor per gt =========
  if (t < G_) {
    unsigned long long gm = ld_agent_u64(&gmax[b * G_ + t]);
    int fa = (int)(~(uint32_t)(gm & 0xFFFFFFFFull));
    size_t fidx = (size_t)b * A_ + fa;
    int old = atomicExch(&labels[fidx], 1);
    if (old != 1) {
      atomicAdd(&counts[b * 2 + 0], 1);
      atomicAdd(&ghist[(b * 2 + 0) * NBUCK + (ld_agent_u32(&vpos[fidx]) >> BSHIFT)], 1);
      if (old == 0) {
        atomicSub(&counts[b * 2 + 1], 1);
        atomicSub(&ghist[(b * 2 + 1) * NBUCK + (ld_agent_u32(&vneg[fidx]) >> BSHIFT)], 1);
      }
    }
  }
  __syncthreads();   // drain force atomics before counts/ghist reads

  // ========== tail: cutoff bucket + remainder (2 rows of this image) ======
  int npos = ld_agent_i32(&counts[b * 2 + 0]);
  int nneg = ld_agent_i32(&counts[b * 2 + 1]);
  int tp = npos < 128 ? npos : 128;
  int tn = 256 - tp; if (nneg < tn) tn = nneg;
  for (int c = 0; c < 2; ++c) {
    const int row = b * 2 + c;
    const int target = (c == 0) ? tp : tn;
    const int* hist = ghist + (size_t)row * NBUCK;
    { int s = 0; const int base = t * 4;
      for (int i = 0; i < 4; i++) s += ld_agent_i32(&hist[base + i]);
      red[t] = s; }
    __syncthreads();
    if (t < 16) { int ss = 0; for (int j = 0; j < 16; j++) ss += red[t * 16 + j]; sup[t] = ss; }
    __syncthreads();
    if (t == 0) {
      int cb = INT_MAX, R = 0;
      if (target > 0) {
        int cum = 0, si = 0;
        for (int i = 15; i >= 0; i--) { if (cum + sup[i] >= target) { si = i; break; } cum += sup[i]; }
        int sj = si * 16;
        for (int j = si * 16 + 15; j >= si * 16; j--) { if (cum + red[j] >= target) { sj = j; break; } cum += red[j]; }
        for (int k = sj * 4 + 3; k >= sj * 4; k--) {
          int hv = ld_agent_i32(&hist[k]);
          if (cum + hv >= target) { cb = k; R = target - cum; break; }
          cum += hv;
        }
      }
      st_agent_i32(&cbR[row * 2 + 0], cb);     // 8 writer blocks: LLC-direct,
      st_agent_i32(&cbR[row * 2 + 1], R);      // byte-granular, no dirty-line
      st_agent_i32(&targets[row], target);     // clobber across XCDs
    }
    __syncthreads();
  }
}

// ---------------------------------------------------------------------------
// K2: merged cand + loss (all blocks); per-image last block ranks that
//     image's cutoff-bucket candidates from LDS; 8th tail writes out.
//     (byte-identical to r21 -- proven codegen, do not re-roll)
// ---------------------------------------------------------------------------
__global__ __launch_bounds__(256) void loss2_k(
    const float* __restrict__ anchors, const float* __restrict__ gtb,
    const float* __restrict__ cls, const float* __restrict__ boxp,
    const int* __restrict__ labels, const int* __restrict__ mgt,
    const uint32_t* __restrict__ vpos, const uint32_t* __restrict__ vneg,
    const int* __restrict__ cbR, const int* __restrict__ targets,
    int* __restrict__ ccnt, uint32_t* __restrict__ cvv, int* __restrict__ cii,
    float* __restrict__ bsums, int* __restrict__ tickets,
    float* __restrict__ out) {
  __shared__ float redf[256];
  __shared__ uint32_t scv[CAP];
  __shared__ int sci[CAP];
  __shared__ int last;

  const int bid = blockIdx.x;
  const int t = threadIdx.x;
  const int b  = bid / NPB;
  const int xb = bid % NPB;
  const int a  = xb * 256 + t;
  const size_t idx = (size_t)b * A_ + a;

  // ========== merged cand + loss ==========================================
  {
    float sb = 0.f, ss = 0.f;
    int lb = labels[idx];
    if (lb >= 0) {
      int c = (lb == 1) ? 0 : 1;
      int row = b * 2 + c;
      uint32_t v = (c == 0 ? vpos : vneg)[idx];
      int bucket = (int)(v >> BSHIFT);
      int cb = cbR[row * 2];
      if (bucket == cb) {
        // deferred: rank unknown until all candidates appended
        int p = atomicAdd(&ccnt[row], 1);
        if (p < CAP) {
          st_agent_u32(&cvv[row * CAP + p], v);   // tail reads cross-XCD
          st_agent_i32(&cii[row * CAP + p], a);
        }
      } else if (bucket > cb) {                  // sure-kept (cb==INT_MAX -> never)
        int kk = a % K_; int hw = a / K_; int hh = hw / W_; int wx = hw % W_;
        float x  = cls[(((size_t)b * K_ + kk) * H_ + hh) * W_ + wx];
        float sp = fmaxf(x, 0.f) + log1pf(expf(-fabsf(x)));   // logaddexp(x,0)
        sb = (lb == 1) ? (sp - x) : sp;
        if (lb == 1) {
          float4 an = ((const float4*)anchors)[a];
          int    mg = mgt[idx];
          float4 gg = ((const float4*)gtb)[b * G_ + mg];
          float tt[4]; encode4(an, gg, tt);
          for (int cc2 = 0; cc2 < 4; cc2++) {
            float p = boxp[(((size_t)b * (4 * K_) + (4 * kk + cc2)) * H_ + hh) * W_ + wx];
            float d = p - tt[cc2];
            float ad = fabsf(d);
            ss += (ad < 1.f) ? (0.5f * d * d) : (ad - 0.5f);
          }
        }
      }
    }
    float sbT = block_reduce_float(sb, redf);
    float ssT = block_reduce_float(ss, redf);
    if (t == 0) {
      if (sbT != 0.f) atomicAdd(&bsums[b * 2 + 0], sbT);
      if (ssT != 0.f) atomicAdd(&bsums[b * 2 + 1], ssT);
    }
  }

  // ---- per-image ticket --------------------------------------------------
  __syncthreads();
  if (t == 0) {
    int v = __hip_atomic_fetch_add(&tickets[8 + b], 1, __ATOMIC_RELAXED,
                                   __HIP_MEMORY_SCOPE_AGENT);
    last = (v == NPB - 1);
  }
  __syncthreads();
  if (!last) return;

  // ========== tail (last image-b block): rank this image's 2 rows =========
  for (int c = 0; c < 2; ++c) {
    const int row = b * 2 + c;
    int c2 = ld_agent_i32(&ccnt[row]); if (c2 > CAP) c2 = CAP;
    const int R = cbR[row * 2 + 1];
    for (int j = t; j < c2; j += 256) {
      scv[j] = ld_agent_u32(&cvv[row * CAP + j]);
      sci[j] = ld_agent_i32(&cii[row * CAP + j]);
    }
    __syncthreads();
    const bool pos = (c == 0);
    float sbl = 0.f, ssl = 0.f;
    for (int j = t; j < c2; j += 256) {
      uint32_t v = scv[j]; int a2 = sci[j];
      int r = 0;
      for (int k2 = 0; k2 < c2; k2++) {
        uint32_t vk = scv[k2]; int ik = sci[k2];
        if (vk > v || (vk == v && ik < a2)) r++;
      }
      if (r < R) {                                // kept: stable-rank subsample
        int kk = a2 % K_; int hw = a2 / K_; int hh = hw / W_; int wx = hw % W_;
        float x = cls[(((size_t)b * K_ + kk) * H_ + hh) * W_ + wx];
        float sp = fmaxf(x, 0.f) + log1pf(expf(-fabsf(x)));
        sbl += pos ? (sp - x) : sp;
        if (pos) {
          float4 an = ((const float4*)anchors)[a2];
          int mg = mgt[(size_t)b * A_ + a2];
          float4 gg = ((const float4*)gtb)[b * G_ + mg];
          float tt[4]; encode4(an, gg, tt);
          for (int cc2 = 0; cc2 < 4; cc2++) {
            float p = boxp[(((size_t)b * (4 * K_) + (4 * kk + cc2)) * H_ + hh) * W_ + wx];
            float d = p - tt[cc2];
            float ad = fabsf(d);
            ssl += (ad < 1.f) ? (0.5f * d * d) : (ad - 0.5f);
          }
        }
      }
    }
    float sbT = block_reduce_float(sbl, redf);
    float ssT = block_reduce_float(ssl, redf);
    if (t == 0) {
      if (sbT != 0.f) atomicAdd(&bsums[b * 2 + 0], sbT);
      if (ssT != 0.f) atomicAdd(&bsums[b * 2 + 1], ssT);
    }
    __syncthreads();
  }

  // ---- final ticket: 8 arrivals, one per image tail ----------------------
  __syncthreads();   // drain bsums atomics
  if (t == 0) {
    int v = __hip_atomic_fetch_add(&tickets[16], 1, __ATOMIC_RELAXED,
                                   __HIP_MEMORY_SCOPE_AGENT);
    last = (v == B_ - 1);
  }
  __syncthreads();
  if (!last) return;

  if (t == 0) {
    float cl = 0.f, bl = 0.f;
    for (int bb = 0; bb < B_; bb++) {
      int tpv = ld_agent_i32(&targets[bb * 2 + 0]);
      int tnv = ld_agent_i32(&targets[bb * 2 + 1]);
      float s0 = ld_agent_f32(&bsums[bb * 2 + 0]);
      float s1 = ld_agent_f32(&bsums[bb * 2 + 1]);
      cl += s0 / fmaxf((float)(tpv + tnv), 1.f);
      bl += s1 / fmaxf(4.f * (float)tpv, 1.f);
    }
    cl *= 0.125f; bl *= 0.125f;
    out[0] = cl; out[1] = bl; out[2] = cl + bl;
  }
}

static void compute_keys(KeyParams& kp) {
  const uint32_t r0 = 0u, r1 = 42u;        // jax.random.key(42) -> (hi, lo)
#if PARTITIONABLE
  for (int b = 0; b < B_; b++) {
    uint32_t kb0, kb1;
    tf2x32(r0, r1, 0u, (uint32_t)b, kb0, kb1);        // split(root, 8)[b]
    uint32_t a0, a1, c0, c1;
    tf2x32(kb0, kb1, 0u, 0u, a0, a1);                 // split(key)[0] = k1
    tf2x32(kb0, kb1, 0u, 1u, c0, c1);                 // split(key)[1] = k2
    kp.k[b][0] = a0; kp.k[b][1] = a1; kp.k[b][2] = c0; kp.k[b][3] = c1;
  }
#else
  uint32_t o0[8], o1[8], flat[16];
  for (int i = 0; i < 8; i++) tf2x32(r0, r1, (uint32_t)i, (uint32_t)(8 + i), o0[i], o1[i]);
  for (int i = 0; i < 8; i++) { flat[i] = o0[i]; flat[8 + i] = o1[i]; }
  for (int b = 0; b < B_; b++) {
    uint32_t kb0 = flat[2 * b], kb1 = flat[2 * b + 1];
    uint32_t a0, b0, a1, b1;
    tf2x32(kb0, kb1, 0u, 2u, a0, b0);
    tf2x32(kb0, kb1, 1u, 3u, a1, b1);
    kp.k[b][0] = a0; kp.k[b][1] = a1; kp.k[b][2] = b0; kp.k[b][3] = b1;
  }
#endif
}

extern "C" void kernel_launch(void* const* d_in, const int* in_sizes, int n_in,
                              void* d_out, int out_size, void* d_ws, size_t ws_size,
                              hipStream_t stream) {
  const float* cls     = (const float*)d_in[0];   // [B,K,H,W]
  const float* boxp    = (const float*)d_in[1];   // [B,4K,H,W]
  const float* anchors = (const float*)d_in[2];   // [A,4]
  const float* gtb     = (const float*)d_in[3];   // [B,G,4]
  float* out = (float*)d_out;

  uint8_t* w = (uint8_t*)d_ws;
  // zeroed region [0, 74240): gmax + ghist + counts + ccnt + bsums + tickets
  unsigned long long* gmax = (unsigned long long*)w;    // B*G u64 (8 KB)
  int*      ghist   = (int*)(w + 8192);                 // 16*NBUCK ints (64 KB)
  int*      counts  = (int*)(w + 73728);                // 16 ints (pad 128)
  int*      ccnt    = (int*)(w + 73856);                // 16 ints (pad 128)
  float*    bsums   = (float*)(w + 73984);              // 16 floats (pad 128)
  int*      tickets = (int*)(w + 74112);                // 32 ints (pad 128):
                                                        // [0..7] K1, [8..15] K2, [16] final
  // non-zeroed region
  int*      labels  = (int*)(w + 74240);                // B*A
  int*      mgt     = labels + (size_t)B_ * A_;         // B*A
  uint32_t* vpos    = (uint32_t*)(mgt + (size_t)B_ * A_);  // B*A
  uint32_t* vneg    = vpos + (size_t)B_ * A_;           // B*A
  int*      cbR     = (int*)(vneg + (size_t)B_ * A_);   // 32
  int*      targets = cbR + 32;                         // 16
  uint32_t* cvv     = (uint32_t*)(targets + 16);        // 16*CAP
  int*      cii     = (int*)(cvv + 16 * CAP);           // 16*CAP

  KeyParams kp;
  compute_keys(kp);

  (void)hipMemsetAsync(w, 0, 74240, stream);
  iou_k<<<NB1, 256, 0, stream>>>(anchors, gtb, labels, mgt, vpos, vneg,
                                 ghist, counts, gmax, cbR, targets, tickets, kp);
  loss2_k<<<NLAB, 256, 0, stream>>>(anchors, gtb, cls, boxp, labels, mgt,
                                    vpos, vneg, cbR, targets, ccnt, cvv, cii,
                                    bsums, tickets, out);
}

// Round 16
// 145.086 us; speedup vs baseline: 1.3677x; 1.3677x over previous
//
#include <hip/hip_runtime.h>
#include <stdint.h>
#include <limits.h>

// ---------------------------------------------------------------------------
// RPN loss, bit-exact replication of the JAX reference (incl. threefry PRNG).
// Round 24 == r14/r21 VERBATIM -- the empirical optimum (144.8/146.5us,
// reproduced twice). Final falsification table (iou_k wall @ ~same busy):
//   r14/r21 57us | r17 101 | r18 104 | r19 100 | r20 105 | r23 107
// Every HIP-source lever (work/thread, DS ops/iter, occupancy, ILP, threefry
// placement, store shape) lands in the ~100-107us basin; only this exact
// source hits 57 (compiler schedule luck that cannot be reverse-engineered
// without disasm). Preserve it.
//  - PER-IMAGE tickets (8 x 144 arrivals): last block of image b runs image
//    b's tail -> tails 8-way parallel, overlapped with other images' bodies.
//  - K2 tail stages the row's ~40 candidates into LDS once, ranks from LDS.
//  - cbR/targets written sc1 (byte-granular at LLC; 8 writers).
//  - final combine gated by an 8-arrival second-level ticket.
// ---------------------------------------------------------------------------
#define PARTITIONABLE 1

#define B_ 8
#define K_ 9
#define H_ 64
#define W_ 64
#define G_ 128
#define A_ 36864            // K*H*W
#define HALF_A 18432
#define NBUCK 1024          // buckets over 23-bit v (v>>13)
#define BSHIFT 13
#define CAP 1024            // cutoff-bucket candidate capacity (expected ~40)
#define NLAB  1152          // (A_/256) * B_  -- one block per 256 anchors
#define NPB   144           // blocks per image = A_/256

struct KeyParams { uint32_t k[B_][4]; };   // per image: k1.(0,1), k2.(0,1)

__host__ __device__ static inline uint32_t rotl32(uint32_t x, int r) {
  return (x << r) | (x >> (32 - r));
}

// JAX threefry2x32: 20 rounds, key injections every 4 rounds.
__host__ __device__ static inline void tf2x32(uint32_t k0, uint32_t k1,
                                              uint32_t x0, uint32_t x1,
                                              uint32_t& o0, uint32_t& o1) {
  uint32_t ks2 = k0 ^ k1 ^ 0x1BD11BDAu;
  x0 += k0; x1 += k1;
#define TF_R(r) { x0 += x1; x1 = rotl32(x1, r); x1 ^= x0; }
  TF_R(13) TF_R(15) TF_R(26) TF_R(6)
  x0 += k1;  x1 += ks2 + 1u;
  TF_R(17) TF_R(29) TF_R(16) TF_R(24)
  x0 += ks2; x1 += k0 + 2u;
  TF_R(13) TF_R(15) TF_R(26) TF_R(6)
  x0 += k0;  x1 += k1 + 3u;
  TF_R(17) TF_R(29) TF_R(16) TF_R(24)
  x0 += k1;  x1 += ks2 + 4u;
  TF_R(13) TF_R(15) TF_R(26) TF_R(6)
  x0 += ks2; x1 += k0 + 5u;
#undef TF_R
  o0 = x0; o1 = x1;
}

// 23-bit sort key of jax.random.uniform(key,(A,))[a]; score monotone in v,
// score ties <=> equal v (stable argsort -> smaller index ranks first).
__device__ static inline uint32_t anchor_vbits(uint32_t k0, uint32_t k1, int a) {
  uint32_t o0, o1;
#if PARTITIONABLE
  tf2x32(k0, k1, 0u, (uint32_t)a, o0, o1);
  return (o0 ^ o1) >> 9;
#else
  if (a < HALF_A) { tf2x32(k0, k1, (uint32_t)a, (uint32_t)(a + HALF_A), o0, o1); return o0 >> 9; }
  else            { tf2x32(k0, k1, (uint32_t)(a - HALF_A), (uint32_t)a, o0, o1); return o1 >> 9; }
#endif
}

// Box area, contraction off (bit-identical to XLA's plain fp32 ops).
__device__ static inline float area_of(float x0, float y0, float x1, float y1) {
#pragma clang fp contract(off)
  return (x1 - x0) * (y1 - y0);
}

// IoU with anchor area hoisted (bit-identical product order, XLA op-by-op).
__device__ static inline float iou_pre_a(float a0, float a1, float a2, float a3,
                                         float area_a,
                                         float g0, float g1, float g2, float g3) {
#pragma clang fp contract(off)
  float ltx = fmaxf(a0, g0), lty = fmaxf(a1, g1);
  float rbx = fminf(a2, g2), rby = fminf(a3, g3);
  float w = rbx - ltx; w = (w < 0.f) ? 0.f : w;
  float h = rby - lty; h = (h < 0.f) ? 0.f : h;
  float inter  = w * h;
  float area_g = (g2 - g0) * (g3 - g1);
  return inter / (area_a + area_g - inter + 1e-6f);
}

__device__ static inline void encode4(float4 an, float4 gg, float* tt) {
#pragma clang fp contract(off)
  float aw  = an.z - an.x,            ah  = an.w - an.y;
  float acx = (an.x + an.z) * 0.5f,   acy = (an.y + an.w) * 0.5f;
  float gw  = gg.z - gg.x,            gh  = gg.w - gg.y;
  float gcx = (gg.x + gg.z) * 0.5f,   gcy = (gg.y + gg.w) * 0.5f;
  tt[0] = (gcx - acx) / aw;
  tt[1] = (gcy - acy) / ah;
  tt[2] = logf(gw / aw);
  tt[3] = logf(gh / ah);
}

__device__ static inline int block_reduce_int(int v, int* sh) {
  int t = threadIdx.x;
  sh[t] = v; __syncthreads();
  for (int s = 128; s > 0; s >>= 1) { if (t < s) sh[t] += sh[t + s]; __syncthreads(); }
  int r = sh[0]; __syncthreads();
  return r;
}
__device__ static inline float block_reduce_float(float v, float* sh) {
  int t = threadIdx.x;
  sh[t] = v; __syncthreads();
  for (int s = 128; s > 0; s >>= 1) { if (t < s) sh[t] += sh[t + s]; __syncthreads(); }
  float r = sh[0]; __syncthreads();
  return r;
}

// Agent-scope (LLC-direct, L2-bypass) relaxed stores/loads: plain-store cost,
// no cache maintenance ops. Used for data a cross-XCD tail block must read.
__device__ static inline void st_agent_i32(int* p, int v) {
  __hip_atomic_store(p, v, __ATOMIC_RELAXED, __HIP_MEMORY_SCOPE_AGENT);
}
__device__ static inline void st_agent_u32(uint32_t* p, uint32_t v) {
  __hip_atomic_store(p, v, __ATOMIC_RELAXED, __HIP_MEMORY_SCOPE_AGENT);
}
__device__ static inline int ld_agent_i32(const int* p) {
  return __hip_atomic_load(p, __ATOMIC_RELAXED, __HIP_MEMORY_SCOPE_AGENT);
}
__device__ static inline uint32_t ld_agent_u32(const uint32_t* p) {
  return __hip_atomic_load(p, __ATOMIC_RELAXED, __HIP_MEMORY_SCOPE_AGENT);
}
__device__ static inline unsigned long long ld_agent_u64(const unsigned long long* p) {
  return __hip_atomic_load(p, __ATOMIC_RELAXED, __HIP_MEMORY_SCOPE_AGENT);
}
__device__ static inline float ld_agent_f32(const float* p) {
  return __hip_atomic_load(p, __ATOMIC_RELAXED, __HIP_MEMORY_SCOPE_AGENT);
}

// ---------------------------------------------------------------------------
// K1: IoU + labels + PRNG + hist + counts (all blocks, r9 body verbatim);
//     per-image last block runs that image's force + cutoff (parallel lanes).
// ---------------------------------------------------------------------------
__global__ __launch_bounds__(256) void iou_k(
    const float* __restrict__ anchors, const float* __restrict__ gtb,
    int* __restrict__ labels, int* __restrict__ mgt,
    uint32_t* __restrict__ vpos, uint32_t* __restrict__ vneg,
    int* __restrict__ ghist, int* __restrict__ counts,
    unsigned long long* __restrict__ gmax,
    int* __restrict__ cbR, int* __restrict__ targets,
    int* __restrict__ tickets, KeyParams kp) {
  __shared__ float2 gp01[2 * G_];               // (x0,y0), duplicated for mod-free idx
  __shared__ float2 gp23[2 * G_];               // (x1,y1), duplicated
  __shared__ unsigned long long slot2[2 * G_];  // per-(block,g residue) best pack
  __shared__ int red[256];
  __shared__ int sup[16];
  __shared__ int last;

  const int bid = blockIdx.x;
  const int t = threadIdx.x;
  const int b  = bid / NPB;
  const int xb = bid % NPB;
  const int a  = xb * 256 + t;                   // < A_ exactly
  const size_t idx = (size_t)b * A_ + a;

  // ========== phase 1: IoU + labels + PRNG + hist + counts ================
  {
    if (t < G_) {
      float4 gg = ((const float4*)gtb)[b * G_ + t];
      float2 p01; p01.x = gg.x; p01.y = gg.y;
      float2 p23; p23.x = gg.z; p23.y = gg.w;
      gp01[t] = p01; gp01[t + G_] = p01;
      gp23[t] = p23; gp23[t + G_] = p23;
    }
    slot2[t] = 0ull;                             // covers all 256 residues
    __syncthreads();

    float4 an = ((const float4*)anchors)[a];
    float area_a = area_of(an.x, an.y, an.z, an.w);
    const int t7 = t & (G_ - 1);
    const unsigned long long alow = (unsigned long long)(~(uint32_t)a);
    unsigned long long blp = 0ull;               // (iou_bits<<32 | g^127) running max
#pragma unroll 4
    for (int s = 0; s < G_; s++) {
      const int gi = t7 + s;                     // in [0, 254]; g = gi & 127
      float2 p01 = gp01[gi];
      float2 p23 = gp23[gi];
      float v = iou_pre_a(an.x, an.y, an.z, an.w, area_a,
                          p01.x, p01.y, p23.x, p23.y);
      unsigned long long hi = (unsigned long long)__float_as_uint(v) << 32;
      unsigned long long lp = hi | (unsigned)((gi & (G_ - 1)) ^ (G_ - 1));
      if (lp > blp) blp = lp;                    // (higher iou, then smaller g)
      atomicMax(&slot2[gi], hi | alow);          // fire-and-forget, lanes distinct
    }
    __syncthreads();
    if (t < G_) {
      unsigned long long p = slot2[t];
      unsigned long long q = slot2[t + G_];
      if (q > p) p = q;
      atomicMax(&gmax[b * G_ + t], p);           // once per (block, g)
    }

    float bv = __uint_as_float((uint32_t)(blp >> 32));
    int   bi = ((int)(blp & (unsigned long long)(G_ - 1))) ^ (G_ - 1);
    int lb = (bv < 0.3f) ? 0 : ((bv >= 0.7f) ? 1 : -1);
    uint32_t vp = anchor_vbits(kp.k[b][0], kp.k[b][1], a);
    uint32_t vn = anchor_vbits(kp.k[b][2], kp.k[b][3], a);
    st_agent_i32(&labels[idx], lb);    // LLC-direct: in-kernel force tail RMWs
    st_agent_u32(&vpos[idx], vp);      // and reads these cross-XCD
    st_agent_u32(&vneg[idx], vn);
    mgt[idx] = bi;                     // only read after dispatch boundary (K2)
    if (lb == 1)      atomicAdd(&ghist[(b * 2 + 0) * NBUCK + (vp >> BSHIFT)], 1);
    else if (lb == 0) atomicAdd(&ghist[(b * 2 + 1) * NBUCK + (vn >> BSHIFT)], 1);
    // packed counts: pos | neg<<16 (block sums <= 256, safe)
    int packed = (lb == 1 ? 1 : 0) | ((lb == 0 ? 1 : 0) << 16);
    int rr = block_reduce_int(packed, red);
    if (t == 0) {
      atomicAdd(&counts[b * 2 + 0], rr & 0xFFFF);
      atomicAdd(&counts[b * 2 + 1], rr >> 16);
    }
  }

  // ---- per-image ticket: syncthreads drains vmcnt (stores acked at LLC) --
  __syncthreads();
  if (t == 0) {
    int v = __hip_atomic_fetch_add(&tickets[b], 1, __ATOMIC_RELAXED,
                                   __HIP_MEMORY_SCOPE_AGENT);
    last = (v == NPB - 1);
  }
  __syncthreads();
  if (!last) return;

  // ========== tail (last image-b block): force best anchor per gt =========
  if (t < G_) {
    unsigned long long gm = ld_agent_u64(&gmax[b * G_ + t]);
    int fa = (int)(~(uint32_t)(gm & 0xFFFFFFFFull));
    size_t fidx = (size_t)b * A_ + fa;
    int old = atomicExch(&labels[fidx], 1);
    if (old != 1) {
      atomicAdd(&counts[b * 2 + 0], 1);
      atomicAdd(&ghist[(b * 2 + 0) * NBUCK + (ld_agent_u32(&vpos[fidx]) >> BSHIFT)], 1);
      if (old == 0) {
        atomicSub(&counts[b * 2 + 1], 1);
        atomicSub(&ghist[(b * 2 + 1) * NBUCK + (ld_agent_u32(&vneg[fidx]) >> BSHIFT)], 1);
      }
    }
  }
  __syncthreads();   // drain force atomics before counts/ghist reads

  // ========== tail: cutoff bucket + remainder (2 rows of this image) ======
  int npos = ld_agent_i32(&counts[b * 2 + 0]);
  int nneg = ld_agent_i32(&counts[b * 2 + 1]);
  int tp = npos < 128 ? npos : 128;
  int tn = 256 - tp; if (nneg < tn) tn = nneg;
  for (int c = 0; c < 2; ++c) {
    const int row = b * 2 + c;
    const int target = (c == 0) ? tp : tn;
    const int* hist = ghist + (size_t)row * NBUCK;
    { int s = 0; const int base = t * 4;
      for (int i = 0; i < 4; i++) s += ld_agent_i32(&hist[base + i]);
      red[t] = s; }
    __syncthreads();
    if (t < 16) { int ss = 0; for (int j = 0; j < 16; j++) ss += red[t * 16 + j]; sup[t] = ss; }
    __syncthreads();
    if (t == 0) {
      int cb = INT_MAX, R = 0;
      if (target > 0) {
        int cum = 0, si = 0;
        for (int i = 15; i >= 0; i--) { if (cum + sup[i] >= target) { si = i; break; } cum += sup[i]; }
        int sj = si * 16;
        for (int j = si * 16 + 15; j >= si * 16; j--) { if (cum + red[j] >= target) { sj = j; break; } cum += red[j]; }
        for (int k = sj * 4 + 3; k >= sj * 4; k--) {
          int hv = ld_agent_i32(&hist[k]);
          if (cum + hv >= target) { cb = k; R = target - cum; break; }
          cum += hv;
        }
      }
      st_agent_i32(&cbR[row * 2 + 0], cb);     // 8 writer blocks: LLC-direct,
      st_agent_i32(&cbR[row * 2 + 1], R);      // byte-granular, no dirty-line
      st_agent_i32(&targets[row], target);     // clobber across XCDs
    }
    __syncthreads();
  }
}

// ---------------------------------------------------------------------------
// K2: merged cand + loss (all blocks); per-image last block ranks that
//     image's cutoff-bucket candidates from LDS; 8th tail writes out.
// ---------------------------------------------------------------------------
__global__ __launch_bounds__(256) void loss2_k(
    const float* __restrict__ anchors, const float* __restrict__ gtb,
    const float* __restrict__ cls, const float* __restrict__ boxp,
    const int* __restrict__ labels, const int* __restrict__ mgt,
    const uint32_t* __restrict__ vpos, const uint32_t* __restrict__ vneg,
    const int* __restrict__ cbR, const int* __restrict__ targets,
    int* __restrict__ ccnt, uint32_t* __restrict__ cvv, int* __restrict__ cii,
    float* __restrict__ bsums, int* __restrict__ tickets,
    float* __restrict__ out) {
  __shared__ float redf[256];
  __shared__ uint32_t scv[CAP];
  __shared__ int sci[CAP];
  __shared__ int last;

  const int bid = blockIdx.x;
  const int t = threadIdx.x;
  const int b  = bid / NPB;
  const int xb = bid % NPB;
  const int a  = xb * 256 + t;
  const size_t idx = (size_t)b * A_ + a;

  // ========== merged cand + loss ==========================================
  {
    float sb = 0.f, ss = 0.f;
    int lb = labels[idx];
    if (lb >= 0) {
      int c = (lb == 1) ? 0 : 1;
      int row = b * 2 + c;
      uint32_t v = (c == 0 ? vpos : vneg)[idx];
      int bucket = (int)(v >> BSHIFT);
      int cb = cbR[row * 2];
      if (bucket == cb) {
        // deferred: rank unknown until all candidates appended
        int p = atomicAdd(&ccnt[row], 1);
        if (p < CAP) {
          st_agent_u32(&cvv[row * CAP + p], v);   // tail reads cross-XCD
          st_agent_i32(&cii[row * CAP + p], a);
        }
      } else if (bucket > cb) {                  // sure-kept (cb==INT_MAX -> never)
        int kk = a % K_; int hw = a / K_; int hh = hw / W_; int wx = hw % W_;
        float x  = cls[(((size_t)b * K_ + kk) * H_ + hh) * W_ + wx];
        float sp = fmaxf(x, 0.f) + log1pf(expf(-fabsf(x)));   // logaddexp(x,0)
        sb = (lb == 1) ? (sp - x) : sp;
        if (lb == 1) {
          float4 an = ((const float4*)anchors)[a];
          int    mg = mgt[idx];
          float4 gg = ((const float4*)gtb)[b * G_ + mg];
          float tt[4]; encode4(an, gg, tt);
          for (int cc2 = 0; cc2 < 4; cc2++) {
            float p = boxp[(((size_t)b * (4 * K_) + (4 * kk + cc2)) * H_ + hh) * W_ + wx];
            float d = p - tt[cc2];
            float ad = fabsf(d);
            ss += (ad < 1.f) ? (0.5f * d * d) : (ad - 0.5f);
          }
        }
      }
    }
    float sbT = block_reduce_float(sb, redf);
    float ssT = block_reduce_float(ss, redf);
    if (t == 0) {
      if (sbT != 0.f) atomicAdd(&bsums[b * 2 + 0], sbT);
      if (ssT != 0.f) atomicAdd(&bsums[b * 2 + 1], ssT);
    }
  }

  // ---- per-image ticket --------------------------------------------------
  __syncthreads();
  if (t == 0) {
    int v = __hip_atomic_fetch_add(&tickets[8 + b], 1, __ATOMIC_RELAXED,
                                   __HIP_MEMORY_SCOPE_AGENT);
    last = (v == NPB - 1);
  }
  __syncthreads();
  if (!last) return;

  // ========== tail (last image-b block): rank this image's 2 rows =========
  for (int c = 0; c < 2; ++c) {
    const int row = b * 2 + c;
    int c2 = ld_agent_i32(&ccnt[row]); if (c2 > CAP) c2 = CAP;
    const int R = cbR[row * 2 + 1];
    for (int j = t; j < c2; j += 256) {
      scv[j] = ld_agent_u32(&cvv[row * CAP + j]);
      sci[j] = ld_agent_i32(&cii[row * CAP + j]);
    }
    __syncthreads();
    const bool pos = (c == 0);
    float sbl = 0.f, ssl = 0.f;
    for (int j = t; j < c2; j += 256) {
      uint32_t v = scv[j]; int a2 = sci[j];
      int r = 0;
      for (int k2 = 0; k2 < c2; k2++) {
        uint32_t vk = scv[k2]; int ik = sci[k2];
        if (vk > v || (vk == v && ik < a2)) r++;
      }
      if (r < R) {                                // kept: stable-rank subsample
        int kk = a2 % K_; int hw = a2 / K_; int hh = hw / W_; int wx = hw % W_;
        float x = cls[(((size_t)b * K_ + kk) * H_ + hh) * W_ + wx];
        float sp = fmaxf(x, 0.f) + log1pf(expf(-fabsf(x)));
        sbl += pos ? (sp - x) : sp;
        if (pos) {
          float4 an = ((const float4*)anchors)[a2];
          int mg = mgt[(size_t)b * A_ + a2];
          float4 gg = ((const float4*)gtb)[b * G_ + mg];
          float tt[4]; encode4(an, gg, tt);
          for (int cc2 = 0; cc2 < 4; cc2++) {
            float p = boxp[(((size_t)b * (4 * K_) + (4 * kk + cc2)) * H_ + hh) * W_ + wx];
            float d = p - tt[cc2];
            float ad = fabsf(d);
            ssl += (ad < 1.f) ? (0.5f * d * d) : (ad - 0.5f);
          }
        }
      }
    }
    float sbT = block_reduce_float(sbl, redf);
    float ssT = block_reduce_float(ssl, redf);
    if (t == 0) {
      if (sbT != 0.f) atomicAdd(&bsums[b * 2 + 0], sbT);
      if (ssT != 0.f) atomicAdd(&bsums[b * 2 + 1], ssT);
    }
    __syncthreads();
  }

  // ---- final ticket: 8 arrivals, one per image tail ----------------------
  __syncthreads();   // drain bsums atomics
  if (t == 0) {
    int v = __hip_atomic_fetch_add(&tickets[16], 1, __ATOMIC_RELAXED,
                                   __HIP_MEMORY_SCOPE_AGENT);
    last = (v == B_ - 1);
  }
  __syncthreads();
  if (!last) return;

  if (t == 0) {
    float cl = 0.f, bl = 0.f;
    for (int bb = 0; bb < B_; bb++) {
      int tpv = ld_agent_i32(&targets[bb * 2 + 0]);
      int tnv = ld_agent_i32(&targets[bb * 2 + 1]);
      float s0 = ld_agent_f32(&bsums[bb * 2 + 0]);
      float s1 = ld_agent_f32(&bsums[bb * 2 + 1]);
      cl += s0 / fmaxf((float)(tpv + tnv), 1.f);
      bl += s1 / fmaxf(4.f * (float)tpv, 1.f);
    }
    cl *= 0.125f; bl *= 0.125f;
    out[0] = cl; out[1] = bl; out[2] = cl + bl;
  }
}

static void compute_keys(KeyParams& kp) {
  const uint32_t r0 = 0u, r1 = 42u;        // jax.random.key(42) -> (hi, lo)
#if PARTITIONABLE
  for (int b = 0; b < B_; b++) {
    uint32_t kb0, kb1;
    tf2x32(r0, r1, 0u, (uint32_t)b, kb0, kb1);        // split(root, 8)[b]
    uint32_t a0, a1, c0, c1;
    tf2x32(kb0, kb1, 0u, 0u, a0, a1);                 // split(key)[0] = k1
    tf2x32(kb0, kb1, 0u, 1u, c0, c1);                 // split(key)[1] = k2
    kp.k[b][0] = a0; kp.k[b][1] = a1; kp.k[b][2] = c0; kp.k[b][3] = c1;
  }
#else
  uint32_t o0[8], o1[8], flat[16];
  for (int i = 0; i < 8; i++) tf2x32(r0, r1, (uint32_t)i, (uint32_t)(8 + i), o0[i], o1[i]);
  for (int i = 0; i < 8; i++) { flat[i] = o0[i]; flat[8 + i] = o1[i]; }
  for (int b = 0; b < B_; b++) {
    uint32_t kb0 = flat[2 * b], kb1 = flat[2 * b + 1];
    uint32_t a0, b0, a1, b1;
    tf2x32(kb0, kb1, 0u, 2u, a0, b0);
    tf2x32(kb0, kb1, 1u, 3u, a1, b1);
    kp.k[b][0] = a0; kp.k[b][1] = a1; kp.k[b][2] = b0; kp.k[b][3] = b1;
  }
#endif
}

extern "C" void kernel_launch(void* const* d_in, const int* in_sizes, int n_in,
                              void* d_out, int out_size, void* d_ws, size_t ws_size,
                              hipStream_t stream) {
  const float* cls     = (const float*)d_in[0];   // [B,K,H,W]
  const float* boxp    = (const float*)d_in[1];   // [B,4K,H,W]
  const float* anchors = (const float*)d_in[2];   // [A,4]
  const float* gtb     = (const float*)d_in[3];   // [B,G,4]
  float* out = (float*)d_out;

  uint8_t* w = (uint8_t*)d_ws;
  // zeroed region [0, 74240): gmax + ghist + counts + ccnt + bsums + tickets
  unsigned long long* gmax = (unsigned long long*)w;    // B*G u64 (8 KB)
  int*      ghist   = (int*)(w + 8192);                 // 16*NBUCK ints (64 KB)
  int*      counts  = (int*)(w + 73728);                // 16 ints (pad 128)
  int*      ccnt    = (int*)(w + 73856);                // 16 ints (pad 128)
  float*    bsums   = (float*)(w + 73984);              // 16 floats (pad 128)
  int*      tickets = (int*)(w + 74112);                // 32 ints (pad 128):
                                                        // [0..7] K1, [8..15] K2, [16] final
  // non-zeroed region
  int*      labels  = (int*)(w + 74240);                // B*A
  int*      mgt     = labels + (size_t)B_ * A_;         // B*A
  uint32_t* vpos    = (uint32_t*)(mgt + (size_t)B_ * A_);  // B*A
  uint32_t* vneg    = vpos + (size_t)B_ * A_;           // B*A
  int*      cbR     = (int*)(vneg + (size_t)B_ * A_);   // 32
  int*      targets = cbR + 32;                         // 16
  uint32_t* cvv     = (uint32_t*)(targets + 16);        // 16*CAP
  int*      cii     = (int*)(cvv + 16 * CAP);           // 16*CAP

  KeyParams kp;
  compute_keys(kp);

  (void)hipMemsetAsync(w, 0, 74240, stream);
  iou_k<<<NLAB, 256, 0, stream>>>(anchors, gtb, labels, mgt, vpos, vneg,
                                  ghist, counts, gmax, cbR, targets, tickets, kp);
  loss2_k<<<NLAB, 256, 0, stream>>>(anchors, gtb, cls, boxp, labels, mgt,
                                    vpos, vneg, cbR, targets, ccnt, cvv, cii,
                                    bsums, tickets, out);
}